// Round 1
// baseline (381.435 us; speedup 1.0000x reference)
//
#include <hip/hip_runtime.h>
#include <hip/hip_bf16.h>

#define N_NODES 50000
#define N_EDGES 800000
#define N_IN    256
#define N_H     64

typedef short short8 __attribute__((ext_vector_type(8)));
typedef float f32x4  __attribute__((ext_vector_type(4)));

__device__ inline short f2bf(float f) {
    __bf16 h = (__bf16)f;                       // RNE convert, compiles to v_cvt (pairs fuse to cvt_pk)
    return (short)__builtin_bit_cast(unsigned short, h);
}
__device__ inline float bflo(unsigned int q) { return __uint_as_float(q << 16); }
__device__ inline float bfhi(unsigned int q) { return __uint_as_float(q & 0xFFFF0000u); }

// ---------------- CSR build ----------------

__global__ void k_hist(const int* __restrict__ adj_rows, const int* __restrict__ diff_rows,
                       int* __restrict__ deg) {
    int e = blockIdx.x * 256 + threadIdx.x;
    if (e < N_EDGES) {
        atomicAdd(&deg[adj_rows[e]], 1);
    } else if (e < 2 * N_EDGES) {
        atomicAdd(&deg[N_NODES + diff_rows[e - N_EDGES]], 1);
    }
}

__global__ void k_scan(const int* __restrict__ deg, int* __restrict__ row_ptr,
                       int* __restrict__ cursor) {
    int g = blockIdx.x;
    const int* d = deg + g * N_NODES;
    int* rp = row_ptr + g * (N_NODES + 1);
    int* cu = cursor + g * N_NODES;
    __shared__ int s[1024];
    int carry = 0;
    for (int base = 0; base < N_NODES; base += 1024) {
        int i = base + (int)threadIdx.x;
        int v = (i < N_NODES) ? d[i] : 0;
        s[threadIdx.x] = v;
        __syncthreads();
        for (int off = 1; off < 1024; off <<= 1) {
            int t = (threadIdx.x >= (unsigned)off) ? s[threadIdx.x - off] : 0;
            __syncthreads();
            s[threadIdx.x] += t;
            __syncthreads();
        }
        int incl = s[threadIdx.x];
        int tot  = s[1023];
        if (i < N_NODES) {
            int ex = carry + incl - v;
            rp[i] = ex;
            cu[i] = ex;
        }
        carry += tot;
        __syncthreads();
    }
    if (threadIdx.x == 0) rp[N_NODES] = carry;
}

__global__ void k_scatter(const int* __restrict__ adj_rows, const int* __restrict__ adj_cols,
                          const float* __restrict__ adj_w,
                          const int* __restrict__ diff_rows, const int* __restrict__ diff_cols,
                          const float* __restrict__ diff_w,
                          int* __restrict__ cursor, int2* __restrict__ csr) {
    int e = blockIdx.x * 256 + threadIdx.x;
    int g, r, c; float w;
    if (e < N_EDGES) {
        g = 0; r = adj_rows[e]; c = adj_cols[e]; w = adj_w[e];
    } else if (e < 2 * N_EDGES) {
        int e2 = e - N_EDGES;
        g = 1; r = diff_rows[e2]; c = diff_cols[e2]; w = diff_w[e2];
    } else return;
    int pos = atomicAdd(&cursor[g * N_NODES + r], 1);
    int2 m; m.x = c; m.y = __float_as_int(w);
    csr[g * N_EDGES + pos] = m;
}

// ---------------- GEMM: T[n][128] (bf16), cols 0..63 = Xa@W, 64..127 = Xb@W ----------------

__global__ __launch_bounds__(256) void k_gemm(
    const float* __restrict__ X0, const float* __restrict__ X1,
    const float* __restrict__ X2, const float* __restrict__ X3,
    const float* __restrict__ W1, const float* __restrict__ W2,
    unsigned short* __restrict__ Tadj, unsigned short* __restrict__ Tdiff) {

    const float* X; const float* W; unsigned short* T; int coloff;
    switch (blockIdx.y) {
        case 0:  X = X0; W = W1; T = Tadj;  coloff = 0;  break;  // h1 = bf@W1
        case 1:  X = X2; W = W1; T = Tadj;  coloff = 64; break;  // h3 = shuf_fts@W1
        case 2:  X = X1; W = W2; T = Tdiff; coloff = 0;  break;  // h2 = bl@W2
        default: X = X3; W = W2; T = Tdiff; coloff = 64; break;  // h4 = shuf_fls@W2
    }

    // W^T in LDS as bf16, padded row stride 264 (bank spread for b128 reads)
    __shared__ __align__(16) unsigned short WT[64][264];
    for (int i = threadIdx.x; i < N_IN * N_H; i += 256) {
        int k = i >> 6, c = i & 63;
        WT[c][k] = (unsigned short)f2bf(W[i]);
    }
    __syncthreads();

    int wid  = threadIdx.x >> 6;
    int lane = threadIdx.x & 63;
    int rb = (blockIdx.x * 4 + wid) * 16;
    if (rb >= N_NODES) return;

    int arow = rb + (lane & 15);
    int kg   = lane >> 4;                       // k-group for A/B fragments
    const float* ap = X + (size_t)arow * N_IN + kg * 8;

    f32x4 acc[4];
    for (int ct = 0; ct < 4; ++ct) acc[ct] = (f32x4){0.f, 0.f, 0.f, 0.f};

    for (int kt = 0; kt < 8; ++kt) {
        const float4* p = reinterpret_cast<const float4*>(ap + kt * 32);
        float4 a0 = p[0];
        float4 a1 = p[1];
        short8 af;
        af[0] = f2bf(a0.x); af[1] = f2bf(a0.y); af[2] = f2bf(a0.z); af[3] = f2bf(a0.w);
        af[4] = f2bf(a1.x); af[5] = f2bf(a1.y); af[6] = f2bf(a1.z); af[7] = f2bf(a1.w);
        #pragma unroll
        for (int ct = 0; ct < 4; ++ct) {
            const unsigned short* wp = &WT[ct * 16 + (lane & 15)][kt * 32 + kg * 8];
            short8 bfr = *reinterpret_cast<const short8*>(wp);
            acc[ct] = __builtin_amdgcn_mfma_f32_16x16x32_bf16(af, bfr, acc[ct], 0, 0, 0);
        }
    }

    // C/D layout: D[row=(lane>>4)*4+r][col=lane&15]
    int rgrp = lane >> 4;
    #pragma unroll
    for (int ct = 0; ct < 4; ++ct) {
        int col = coloff + ct * 16 + (lane & 15);
        #pragma unroll
        for (int r = 0; r < 4; ++r) {
            int row = rb + rgrp * 4 + r;
            T[(size_t)row * 128 + col] = (unsigned short)f2bf(acc[ct][r]);
        }
    }
}

// ---------------- Aggregate (gather) + bias + PReLU, writes final output ----------------

__global__ __launch_bounds__(256) void k_agg(
    const int* __restrict__ row_ptr, const int2* __restrict__ csr,
    const unsigned int* __restrict__ Tadj, const unsigned int* __restrict__ Tdiff,
    const float* __restrict__ b1, const float* __restrict__ a1,
    const float* __restrict__ b2, const float* __restrict__ a2,
    float* __restrict__ out) {

    int wid  = threadIdx.x >> 6;
    int lane = threadIdx.x & 63;
    int node = blockIdx.x * 4 + wid;
    int g    = blockIdx.y;

    const int* rp = row_ptr + g * (N_NODES + 1);
    const int2* el = csr + g * N_EDGES;
    const unsigned int* Tu = g ? Tdiff : Tadj;   // 64 dwords per node row (128 bf16)

    int e  = rp[node];
    int e1 = rp[node + 1];
    float ax = 0.f, ay = 0.f;

    for (; e + 4 <= e1; e += 4) {
        int2 m0 = el[e + 0], m1 = el[e + 1], m2 = el[e + 2], m3 = el[e + 3];
        unsigned int q0 = Tu[(size_t)m0.x * 64 + lane];
        unsigned int q1 = Tu[(size_t)m1.x * 64 + lane];
        unsigned int q2 = Tu[(size_t)m2.x * 64 + lane];
        unsigned int q3 = Tu[(size_t)m3.x * 64 + lane];
        float w0 = __int_as_float(m0.y), w1 = __int_as_float(m1.y);
        float w2 = __int_as_float(m2.y), w3 = __int_as_float(m3.y);
        ax += w0 * bflo(q0); ay += w0 * bfhi(q0);
        ax += w1 * bflo(q1); ay += w1 * bfhi(q1);
        ax += w2 * bflo(q2); ay += w2 * bfhi(q2);
        ax += w3 * bflo(q3); ay += w3 * bfhi(q3);
    }
    for (; e < e1; ++e) {
        int2 m = el[e];
        unsigned int q = Tu[(size_t)m.x * 64 + lane];
        float w = __int_as_float(m.y);
        ax += w * bflo(q); ay += w * bfhi(q);
    }

    // features f = 2*lane, 2*lane+1 in [0,128): lane<32 -> first output, lane>=32 -> second
    const float* bias = g ? b2 : b1;
    float slope = g ? a2[0] : a1[0];
    int f = 2 * lane;
    size_t base;
    int fo;
    if (lane < 32) { base = g ? (size_t)3200000 : (size_t)0;       fo = f; }
    else           { base = g ? (size_t)9600000 : (size_t)6400000; fo = f - 64; }
    float v0 = ax + bias[fo];
    float v1 = ay + bias[fo + 1];
    v0 = (v0 >= 0.f) ? v0 : slope * v0;
    v1 = (v1 >= 0.f) ? v1 : slope * v1;
    float2 res; res.x = v0; res.y = v1;
    *reinterpret_cast<float2*>(out + base + (size_t)node * 64 + fo) = res;
}

// ---------------- launch ----------------

extern "C" void kernel_launch(void* const* d_in, const int* in_sizes, int n_in,
                              void* d_out, int out_size, void* d_ws, size_t ws_size,
                              hipStream_t stream) {
    const float* bf_      = (const float*)d_in[0];
    const float* bl_      = (const float*)d_in[1];
    const float* shuf_fts = (const float*)d_in[2];
    const float* shuf_fls = (const float*)d_in[3];
    const int*   adj_rows = (const int*)d_in[4];
    const int*   adj_cols = (const int*)d_in[5];
    const float* adj_w    = (const float*)d_in[6];
    const int*   diff_rows= (const int*)d_in[7];
    const int*   diff_cols= (const int*)d_in[8];
    const float* diff_w   = (const float*)d_in[9];
    const float* W1       = (const float*)d_in[10];
    const float* b1       = (const float*)d_in[11];
    const float* a1       = (const float*)d_in[12];
    const float* W2       = (const float*)d_in[13];
    const float* b2       = (const float*)d_in[14];
    const float* a2       = (const float*)d_in[15];
    float* out = (float*)d_out;

    char* ws = (char*)d_ws;
    // workspace layout
    unsigned short* Tadj  = (unsigned short*)(ws);                         // 12.8 MB
    unsigned short* Tdiff = (unsigned short*)(ws + 12800000);              // 12.8 MB
    int2* csr             = (int2*)(ws + 25600000);                        // 12.8 MB
    int*  deg             = (int*)(ws + 38400000);                         // 400 KB
    int*  row_ptr         = (int*)(ws + 38800000);                         // ~400 KB
    int*  cursor          = (int*)(ws + 39200256);                         // 400 KB

    hipMemsetAsync(deg, 0, 2 * N_NODES * sizeof(int), stream);

    k_hist<<<dim3((2 * N_EDGES + 255) / 256), dim3(256), 0, stream>>>(adj_rows, diff_rows, deg);
    k_scan<<<dim3(2), dim3(1024), 0, stream>>>(deg, row_ptr, cursor);
    k_scatter<<<dim3((2 * N_EDGES + 255) / 256), dim3(256), 0, stream>>>(
        adj_rows, adj_cols, adj_w, diff_rows, diff_cols, diff_w, cursor, csr);

    k_gemm<<<dim3((N_NODES + 63) / 64, 4), dim3(256), 0, stream>>>(
        bf_, bl_, shuf_fts, shuf_fls, W1, W2, Tadj, Tdiff);

    k_agg<<<dim3(N_NODES / 4, 2), dim3(256), 0, stream>>>(
        row_ptr, csr, (const unsigned int*)Tadj, (const unsigned int*)Tdiff,
        b1, a1, b2, a2, out);
}